// Round 5
// baseline (75923.022 us; speedup 1.0000x reference)
//
#include <hip/hip_runtime.h>
#include <stdint.h>
#include <stddef.h>

// LSTMNetwork: 3-layer stacked LSTM, batch=1, T=4096, IN=64, H=1024, OUT=1.
//
// Round 13: R11 base (u32 LSB-validity slots, 640 blocks, register-resident
// weights) + two targeted changes:
//   1. Per-element absorb with LDS group flags. Staging wave FMAs each
//      element the moment it becomes valid (lane l polls exactly the element
//      its own partial dot-product needs), stages it to LDS, and sets a
//      monotone per-group flag (value t+1, fenced) when the group of 64
//      completes. Sibling waves FMA remote groups opportunistically, then
//      spin on LDS flags (no LLC traffic). Removes R11's __all 4-group
//      quantization (one straggler => full extra LLC round for the wave)
//      and overlaps FMA with straggler wait.
//   2. x-role poll backoff (s_sleep(16) between failed rounds). x-blocks'
//      detect lag adds only to inter-layer skew (self-adjusting, free with
//      full-history buffers), not to the recurrence period -- but their
//      polls are half the readers hammering the hot line during the publish
//      window. h-blocks: token s_sleep(1) after round 2.
//   Evidence: R9 6.0us/step @256 readers/line; R11 6.3 @256 (half bytes:
//   null); R12 9.2 @1024 readers/line => reader pressure is the live
//   variable; post-detect serialization is the other addressable term.
//   Skew guard: one __syncthreads per step (bounds wave drift to <1 iter;
//   double-buffered LDS row). Deadlock-free: all exchange is write-once
//   monotone; co-residency not required for progress.

#define T_STEPS 4096
#define HD      1024
#define NBH     128        // h-blocks (and x-blocks) per layer

typedef unsigned long long u64;
typedef uint32_t u32;

// Module .bss (~176 MB). Harness never pokes these.
__device__ u32 g_valA[(size_t)T_STEPS * HD];    // layer0 h history (16MB)
__device__ u32 g_valB[(size_t)T_STEPS * HD];    // layer1 h history (16MB)
__device__ u32 g_valC[(size_t)T_STEPS * HD];    // layer2 h history (16MB)
__device__ u32 g_pre1[(size_t)T_STEPS * 4096];  // layer1 gate preacts (64MB)
__device__ u32 g_pre2[(size_t)T_STEPS * 4096];  // layer2 gate preacts (64MB)

__device__ __forceinline__ float fsig(float x)  { return 1.0f / (1.0f + __expf(-x)); }
__device__ __forceinline__ float ftanh(float x) { return 1.0f - 2.0f / (__expf(2.0f * x) + 1.0f); }

__global__ __launch_bounds__(256)
void init_bufs()
{
    const size_t gtid = (size_t)blockIdx.x * blockDim.x + threadIdx.x;
    const size_t step = (size_t)gridDim.x * blockDim.x;
    const size_t nh = (size_t)T_STEPS * HD;
    const size_t np = (size_t)T_STEPS * 4096;
    for (size_t i = gtid; i < nh; i += step) { g_valA[i] = 1u; g_valB[i] = 1u; g_valC[i] = 1u; }
    for (size_t i = gtid; i < np; i += step) { g_pre1[i] = 1u; g_pre2[i] = 1u; }
}

__global__ __launch_bounds__(256, 3)   // 640 blocks, 3 blocks/CU cap
void fused_scan(const float* __restrict__ seq,
                const float* __restrict__ wih0, const float* __restrict__ whh0_,
                const float* __restrict__ bih0, const float* __restrict__ bhh0,
                const float* __restrict__ wih1, const float* __restrict__ whh1_,
                const float* __restrict__ bih1, const float* __restrict__ bhh1,
                const float* __restrict__ wih2, const float* __restrict__ whh2_,
                const float* __restrict__ bih2, const float* __restrict__ bhh2)
{
    __shared__ float s_buf[2][HD];            // staged source row (double-buffered)
    volatile __shared__ u32 s_flag[16];       // per-group "staged through step" flags

    const int bid  = blockIdx.x;
    const int lane = threadIdx.x & 63;
    const int wave = threadIdx.x >> 6;

    const bool isH  = (bid < 3 * NBH);
    const int layer = isH ? (bid >> 7) : (1 + ((bid - 3 * NBH) >> 7));
    const int bu    = isH ? (bid & (NBH - 1)) : ((bid - 3 * NBH) & (NBH - 1));
    const int j0    = bu * 8 + wave * 2;       // first of this wave's 2 units
    const int k     = lane & 7;                // acc index this lane finalizes (u*4+g)
    const int rk    = ((k & 3) << 10) + j0 + (k >> 2);   // its gate-row in [4H]

    // ---- role pointers ----
    const float* Wmat;
    const u32*  srcVal;
    u32*        valOut = nullptr;
    u32*        preOut = nullptr;
    const u32*  preIn  = nullptr;
    float       biasL  = 0.f;

    if (isH) {
        Wmat   = (layer == 0) ? whh0_ : (layer == 1) ? whh1_ : whh2_;
        valOut = (layer == 0) ? g_valA : (layer == 1) ? g_valB : g_valC;
        srcVal = valOut;                       // own history
        if (layer == 1) preIn = g_pre1;
        if (layer == 2) preIn = g_pre2;
        if (layer == 0) biasL = bih0[rk] + bhh0[rk];
    } else {
        Wmat   = (layer == 1) ? wih1 : wih2;
        srcVal = (layer == 1) ? g_valA : g_valB;
        preOut = (layer == 1) ? g_pre1 : g_pre2;
        biasL  = (layer == 1) ? (bih1[rk] + bhh1[rk]) : (bih2[rk] + bhh2[rk]);
    }

    // ---- weights into registers: 8 gate-rows (2 units x 4 gates) x 16 ----
    // W[r][i] multiplies source element i*64 + lane.
    float W[8][16];
#pragma unroll
    for (int u = 0; u < 2; ++u)
#pragma unroll
        for (int g = 0; g < 4; ++g) {
            const float* pr = Wmat + (size_t)((g << 10) + j0 + u) * HD;
#pragma unroll
            for (int i = 0; i < 16; ++i) W[u * 4 + g][i] = pr[(i << 6) + lane];
        }

    float wi0[8];
    if (isH && layer == 0) {
#pragma unroll
        for (int kk = 0; kk < 8; ++kk)
            wi0[kk] = wih0[(size_t)(((kk & 3) << 10) + j0 + (kk >> 2)) * 64 + lane];
    }

    if (threadIdx.x < 16) s_flag[threadIdx.x] = 0u;
    __syncthreads();

    float c = 0.f;
    const int grp0 = wave << 2;   // this wave's first group (stages groups grp0..grp0+3)

    for (int t = 0; t < T_STEPS; ++t) {
        const int p = t & 1;
        const u32 want = (u32)(t + 1);
        u32 preBits = 1u; float xv = 0.f;
        const bool needRow = (!isH) || (t > 0);

        // ---- early probes ----
        if (isH) {
            if (layer == 0) {
                xv = seq[(size_t)t * 64 + lane];
            } else {
                preBits = __hip_atomic_load(preIn + (size_t)t * 4096 + (j0 << 2) + k,
                                            __ATOMIC_RELAXED, __HIP_MEMORY_SCOPE_AGENT);
            }
        }

        // ---- accumulators (x-term for L0) ----
        float a0, a1, a2, a3, a4, a5, a6, a7;
        if (isH && layer == 0) {
            a0 = wi0[0] * xv; a1 = wi0[1] * xv; a2 = wi0[2] * xv; a3 = wi0[3] * xv;
            a4 = wi0[4] * xv; a5 = wi0[5] * xv; a6 = wi0[6] * xv; a7 = wi0[7] * xv;
        } else {
            a0 = a1 = a2 = a3 = a4 = a5 = a6 = a7 = 0.f;
        }

#define FMA_GRP(G, HV)                                   \
        do {                                             \
            const float _h = (HV);                       \
            a0 = __fmaf_rn(W[0][G], _h, a0);             \
            a1 = __fmaf_rn(W[1][G], _h, a1);             \
            a2 = __fmaf_rn(W[2][G], _h, a2);             \
            a3 = __fmaf_rn(W[3][G], _h, a3);             \
            a4 = __fmaf_rn(W[4][G], _h, a4);             \
            a5 = __fmaf_rn(W[5][G], _h, a5);             \
            a6 = __fmaf_rn(W[6][G], _h, a6);             \
            a7 = __fmaf_rn(W[7][G], _h, a7);             \
        } while (0)

        if (needRow) {
            const u32* rowp = srcVal + (size_t)(isH ? (t - 1) : t) * HD;

            // ---- stage own quarter: absorb per element, flag per group ----
            u32 todo = 0xFu, flagged = 0u;
            int round = 0;
            while (__any(todo)) {
                if (round > 0) {
                    if (!isH)            __builtin_amdgcn_s_sleep(16);  // skew-only cost
                    else if (round > 1)  __builtin_amdgcn_s_sleep(1);
                }
#pragma unroll
                for (int i = 0; i < 4; ++i) if (todo & (1u << i)) {
                    const u32 v = __hip_atomic_load(rowp + ((grp0 + i) << 6) + lane,
                                                    __ATOMIC_RELAXED, __HIP_MEMORY_SCOPE_AGENT);
                    if (!(v & 1u)) {
                        const float hv = __uint_as_float(v);
                        FMA_GRP(grp0 + i, hv);
                        s_buf[p][((grp0 + i) << 6) + lane] = hv;
                        todo &= ~(1u << i);
                    }
                }
                // publish completed groups to sibling waves (fence: data first)
                u32 newly = 0u;
#pragma unroll
                for (int i = 0; i < 4; ++i)
                    if (!(flagged & (1u << i)) && __all((todo & (1u << i)) == 0u))
                        newly |= (1u << i);
                if (newly) {
                    __threadfence_block();
                    if (lane == 0) {
#pragma unroll
                        for (int i = 0; i < 4; ++i)
                            if (newly & (1u << i)) s_flag[grp0 + i] = want;
                    }
                    flagged |= newly;
                }
                ++round;
            }

            // ---- remote groups: opportunistic pass, then LDS-flag spin ----
            u32 rem = 0xFFFFu & ~(0xFu << grp0);
            const volatile float* vsp =
                reinterpret_cast<volatile float*>(&s_buf[p][0]);
#pragma unroll
            for (int g = 0; g < 16; ++g)
                if (rem & (1u << g))
                    if (s_flag[g] >= want) { FMA_GRP(g, vsp[(g << 6) | lane]); rem &= ~(1u << g); }
            while (rem) {
#pragma unroll
                for (int g = 0; g < 16; ++g)
                    if (rem & (1u << g))
                        if (s_flag[g] >= want) { FMA_GRP(g, vsp[(g << 6) | lane]); rem &= ~(1u << g); }
                if (rem) __builtin_amdgcn_s_sleep(1);
            }
        }
#undef FMA_GRP

        // ---- scatter-butterfly reduce: lane l ends with 64-lane sum of acc (l&7) ----
        float e;
        {
            const int l1 = lane & 1, l2 = lane & 2, l4 = lane & 4;
            const float s0 = __shfl_xor(a0, 1, 64), s1 = __shfl_xor(a1, 1, 64);
            const float s2 = __shfl_xor(a2, 1, 64), s3 = __shfl_xor(a3, 1, 64);
            const float s4 = __shfl_xor(a4, 1, 64), s5 = __shfl_xor(a5, 1, 64);
            const float s6 = __shfl_xor(a6, 1, 64), s7 = __shfl_xor(a7, 1, 64);
            const float c0 = l1 ? (a1 + s1) : (a0 + s0);
            const float c1 = l1 ? (a3 + s3) : (a2 + s2);
            const float c2 = l1 ? (a5 + s5) : (a4 + s4);
            const float c3 = l1 ? (a7 + s7) : (a6 + s6);
            const float u0 = __shfl_xor(c0, 2, 64), u1 = __shfl_xor(c1, 2, 64);
            const float u2 = __shfl_xor(c2, 2, 64), u3 = __shfl_xor(c3, 2, 64);
            const float d0 = l2 ? (c1 + u1) : (c0 + u0);
            const float d1 = l2 ? (c3 + u3) : (c2 + u2);
            const float v0 = __shfl_xor(d0, 4, 64), v1 = __shfl_xor(d1, 4, 64);
            e = l4 ? (d1 + v1) : (d0 + v0);
            e += __shfl_xor(e, 8, 64);
            e += __shfl_xor(e, 16, 64);
            e += __shfl_xor(e, 32, 64);
        }

        // ---- epilogue ----
        if (isH) {
            float add;
            if (layer == 0) {
                add = biasL;
            } else {
                while (__any(preBits & 1u)) {
                    __builtin_amdgcn_s_sleep(1);
                    if (preBits & 1u)
                        preBits = __hip_atomic_load(preIn + (size_t)t * 4096 + (j0 << 2) + k,
                                                    __ATOMIC_RELAXED, __HIP_MEMORY_SCOPE_AGENT);
                }
                add = __uint_as_float(preBits);   // preact carries Wih.x + b_ih + b_hh
            }
            const float val = e + add;
            // gate nonlinearity: k&3 == 2 is the g-gate (tanh), others sigmoid
            const float av = ((lane & 3) == 2) ? ftanh(val) : fsig(val);
            const int gb = lane & ~3;
            const float iv = __shfl(av, gb + 0, 64);
            const float fv = __shfl(av, gb + 1, 64);
            const float gv = __shfl(av, gb + 2, 64);
            const float ov = __shfl(av, gb + 3, 64);
            c = __fmaf_rn(fv, c, iv * gv);
            const float h = ov * ftanh(c);
            if (lane == 0 || lane == 4) {
                __hip_atomic_store(valOut + (size_t)t * HD + j0 + (lane >> 2),
                                   __float_as_uint(h) & ~1u,
                                   __ATOMIC_RELAXED, __HIP_MEMORY_SCOPE_AGENT);
            }
        } else {
            const float val = e + biasL;
            if (lane < 8)
                __hip_atomic_store(preOut + (size_t)t * 4096 + (j0 << 2) + lane,
                                   __float_as_uint(val) & ~1u,
                                   __ATOMIC_RELAXED, __HIP_MEMORY_SCOPE_AGENT);
        }

        __syncthreads();   // skew guard: bounds wave drift to < 1 iteration
    }
}

__global__ __launch_bounds__(256)
void final_kernel(const float* __restrict__ w_lin,
                  const float* __restrict__ b_lin,
                  float*       __restrict__ out)
{
    __shared__ float red[256];
    const int tid = threadIdx.x;
    const u32* vrow = g_valC + (size_t)(T_STEPS - 1) * HD;
    float s = 0.f;
#pragma unroll
    for (int i = 0; i < 4; ++i) {
        const int kk = tid + 256 * i;
        s += __uint_as_float(vrow[kk]) * w_lin[kk];
    }
    red[tid] = s;
    __syncthreads();
    for (int o = 128; o > 0; o >>= 1) {
        if (tid < o) red[tid] += red[tid + o];
        __syncthreads();
    }
    if (tid == 0) out[0] = red[0] + b_lin[0];
}

extern "C" void kernel_launch(void* const* d_in, const int* in_sizes, int n_in,
                              void* d_out, int out_size, void* d_ws, size_t ws_size,
                              hipStream_t stream)
{
    (void)in_sizes; (void)n_in; (void)out_size; (void)d_ws; (void)ws_size;

    const float* seq   = (const float*)d_in[0];
    const float* w_ih0 = (const float*)d_in[1];
    const float* w_hh0 = (const float*)d_in[2];
    const float* b_ih0 = (const float*)d_in[3];
    const float* b_hh0 = (const float*)d_in[4];
    const float* w_ih1 = (const float*)d_in[5];
    const float* w_hh1 = (const float*)d_in[6];
    const float* b_ih1 = (const float*)d_in[7];
    const float* b_hh1 = (const float*)d_in[8];
    const float* w_ih2 = (const float*)d_in[9];
    const float* w_hh2 = (const float*)d_in[10];
    const float* b_ih2 = (const float*)d_in[11];
    const float* b_hh2 = (const float*)d_in[12];
    const float* w_lin = (const float*)d_in[13];
    const float* b_lin = (const float*)d_in[14];

    // Replay hygiene: all slots back to "unwritten" (LSB=1) each launch.
    init_bufs<<<dim3(2048), dim3(256), 0, stream>>>();

    // Blocks [0,384) = h-role (128/layer); [384,640) = x-role (128 for L1, L2).
    fused_scan<<<dim3(640), dim3(256), 0, stream>>>(
        seq,
        w_ih0, w_hh0, b_ih0, b_hh0,
        w_ih1, w_hh1, b_ih1, b_hh1,
        w_ih2, w_hh2, b_ih2, b_hh2);

    final_kernel<<<dim3(1), dim3(256), 0, stream>>>(w_lin, b_lin, (float*)d_out);
}

// Round 6
// 22411.153 us; speedup vs baseline: 3.3877x; 3.3877x over previous
//
#include <hip/hip_runtime.h>
#include <stdint.h>
#include <stddef.h>

// LSTMNetwork: 3-layer stacked LSTM, batch=1, T=4096, IN=64, H=1024, OUT=1.
//
// Round 14: R9-exact base (measured best: 24.36 ms) + two hot-window
// pressure cuts. R13's lesson (107 GB scratch-spill FETCH): the poll loop
// must touch nothing but address/value/LDS; all weight-FMA stays in the
// straight-line unrolled block (84 VGPR + ~86 AGPR = fits 3 waves/SIMD).
//   1. Mirror publish: L0/L1 h-producers store each h slot to primary AND
//      mirror; x-blocks poll the mirror. Hot h-row readers/line 256 -> 128
//      per copy (R12 arithmetic: ~4 ns/reader/line contention term).
//   2. x-role poll backoff (s_sleep(4) ~107ns after a failed round):
//      x-detect lag is self-correcting pipeline slack (full-history
//      buffers); their tight polls steal CU issue slots from co-resident
//      h-blocks and hammer lines during the publish window.
//   Exchange: 64-bit tagged slots [tag32|fp32], relaxed agent-scope atomics
//   (no fences -- R10 lesson). Layers 0/1 full history; layer 2 16-row ring.
//   Grid 640 @ __launch_bounds__(256,3): all co-resident.

#define T_STEPS 4096
#define HD      1024
#define RINGR   16
#define NBH     128

#define TAGL0 0x10000000u
#define TAGL1 0x30000000u
#define TAGL2 0x50000000u
#define TAGP1 0x70000000u
#define TAGP2 0x90000000u

typedef unsigned long long u64;
typedef uint32_t u32;

// Module .bss (~448 MB). Harness never pokes these.
__device__ u64 g_bufA[(size_t)T_STEPS * HD];    // layer0 h history (32 MB)
__device__ u64 g_bufB[(size_t)T_STEPS * HD];    // layer1 h history (32 MB)
__device__ u64 g_ring[RINGR * HD];              // layer2 h ring (128 KB)
__device__ u64 g_mirA[(size_t)T_STEPS * HD];    // layer0 h mirror for x-readers (32 MB)
__device__ u64 g_mirB[(size_t)T_STEPS * HD];    // layer1 h mirror for x-readers (32 MB)
__device__ u64 g_pre1[(size_t)T_STEPS * 4096];  // layer1 gate preacts (128 MB)
__device__ u64 g_pre2[(size_t)T_STEPS * 4096];  // layer2 gate preacts (128 MB)

__device__ __forceinline__ float fsig(float x)  { return 1.0f / (1.0f + __expf(-x)); }
__device__ __forceinline__ float ftanh(float x) { return 1.0f - 2.0f / (__expf(2.0f * x) + 1.0f); }

__global__ __launch_bounds__(256)
void zero_bufs()
{
    const size_t gtid = (size_t)blockIdx.x * blockDim.x + threadIdx.x;
    const size_t step = (size_t)gridDim.x * blockDim.x;
    const size_t nh = (size_t)T_STEPS * HD;
    for (size_t i = gtid; i < nh; i += step) {
        g_bufA[i] = 0ULL; g_bufB[i] = 0ULL; g_mirA[i] = 0ULL; g_mirB[i] = 0ULL;
    }
    for (size_t i = gtid; i < (size_t)RINGR * HD; i += step) g_ring[i] = 0ULL;
}

__global__ __launch_bounds__(256, 3)   // 640 blocks, 3 blocks/CU cap => all co-resident
void fused_scan(const float* __restrict__ seq,
                const float* __restrict__ wih0, const float* __restrict__ whh0_,
                const float* __restrict__ bih0, const float* __restrict__ bhh0,
                const float* __restrict__ wih1, const float* __restrict__ whh1_,
                const float* __restrict__ bih1, const float* __restrict__ bhh1,
                const float* __restrict__ wih2, const float* __restrict__ whh2_,
                const float* __restrict__ bih2, const float* __restrict__ bhh2)
{
    __shared__ float s_buf[2][HD];   // staged source row (own-h for h-role, upstream-h for x-role)

    const int bid  = blockIdx.x;
    const int lane = threadIdx.x & 63;
    const int wave = threadIdx.x >> 6;

    const bool isH  = (bid < 3 * NBH);
    const int layer = isH ? (bid >> 7) : (1 + ((bid - 3 * NBH) >> 7));
    const int bu    = isH ? (bid & (NBH - 1)) : ((bid - 3 * NBH) & (NBH - 1));
    const int j0    = bu * 8 + wave * 2;       // first of this wave's 2 units
    const int k     = lane & 7;                // acc index this lane finalizes (u*4+g)
    const int rk    = ((k & 3) << 10) + j0 + (k >> 2);   // its gate-row in [4H]

    // ---- role pointers ----
    const float* Wmat;
    const u64*  srcVal;  uint32_t srcTagB, srcRowM = 0xFFFFFFFFu;
    u64*        valOut = nullptr;   u64* mirOut = nullptr;
    u64*        preOut = nullptr;
    const u64*  preIn  = nullptr;
    uint32_t    myTagB = 0, preTagB = 0;
    float       biasL  = 0.f;

    if (isH) {
        Wmat    = (layer == 0) ? whh0_ : (layer == 1) ? whh1_ : whh2_;
        valOut  = (layer == 0) ? g_bufA : (layer == 1) ? g_bufB : g_ring;
        mirOut  = (layer == 0) ? g_mirA : (layer == 1) ? g_mirB : nullptr;
        myTagB  = (layer == 0) ? TAGL0 : (layer == 1) ? TAGL1 : TAGL2;
        srcRowM = (layer == 2) ? (RINGR - 1) : 0xFFFFFFFFu;
        srcVal  = valOut; srcTagB = myTagB;     // own history
        if (layer == 1) { preIn = g_pre1; preTagB = TAGP1; }
        if (layer == 2) { preIn = g_pre2; preTagB = TAGP2; }
        if (layer == 0) biasL = bih0[rk] + bhh0[rk];
    } else {
        Wmat    = (layer == 1) ? wih1 : wih2;
        srcVal  = (layer == 1) ? g_mirA : g_mirB;          // read the MIRROR
        srcTagB = (layer == 1) ? TAGL0 : TAGL1;
        preOut  = (layer == 1) ? g_pre1 : g_pre2;
        preTagB = (layer == 1) ? TAGP1 : TAGP2;
        biasL   = (layer == 1) ? (bih1[rk] + bhh1[rk]) : (bih2[rk] + bhh2[rk]);
    }

    // ---- weights into registers: 8 gate-rows (2 units x 4 gates) x 16 ----
    float W[8][16];
#pragma unroll
    for (int u = 0; u < 2; ++u)
#pragma unroll
        for (int g = 0; g < 4; ++g) {
            const float* pr = Wmat + (size_t)((g << 10) + j0 + u) * HD;
#pragma unroll
            for (int i = 0; i < 16; ++i) W[u * 4 + g][i] = pr[(i << 6) + lane];
        }

    float wi0[8];
    if (isH && layer == 0) {
#pragma unroll
        for (int kk = 0; kk < 8; ++kk)
            wi0[kk] = wih0[(size_t)(((kk & 3) << 10) + j0 + (kk >> 2)) * 64 + lane];
    }

    float c = 0.f;
    const int sb = wave << 8;    // this wave's staging quarter [sb, sb+256)

    for (int t = 0; t < T_STEPS; ++t) {
        const int p = t & 1;
        u64 pre = 0; float xv = 0.f;
        const bool needRow = (!isH) || (t > 0);

        // ---- early preact probe (one line, >=1 pipeline slot of slack) ----
        if (isH) {
            if (layer == 0) {
                xv = seq[(size_t)t * 64 + lane];
            } else {
                pre = __hip_atomic_load(preIn + (size_t)t * 4096 + (j0 << 2) + k,
                                        __ATOMIC_RELAXED, __HIP_MEMORY_SCOPE_AGENT);
            }
        }

        // ---- staging: poll own quarter of source row, stage incrementally ----
        if (needRow) {
            const uint32_t stag = srcTagB + (uint32_t)(isH ? (t - 1) : t);
            const u64* rowp = srcVal
                + (size_t)((uint32_t)(isH ? (t - 1) : t) & srcRowM) * HD;
            u32 todo = 0xFu;
            bool first = true;
            while (__any(todo)) {
                if (!first && !isH) __builtin_amdgcn_s_sleep(4);   // x: ~107ns backoff
                first = false;
#pragma unroll
                for (int i = 0; i < 4; ++i) if (todo & (1u << i)) {
                    const u64 u = __hip_atomic_load(rowp + sb + (i << 6) + lane,
                                                    __ATOMIC_RELAXED, __HIP_MEMORY_SCOPE_AGENT);
                    if ((uint32_t)(u >> 32) == stag) {
                        s_buf[p][sb + (i << 6) + lane] = __uint_as_float((uint32_t)u);
                        todo &= ~(1u << i);
                    }
                }
            }
        }
        __syncthreads();

        // ---- 8 gate dot-products (per-lane partials) ----
        float a0, a1, a2, a3, a4, a5, a6, a7;
        if (isH && layer == 0) {
            a0 = wi0[0] * xv; a1 = wi0[1] * xv; a2 = wi0[2] * xv; a3 = wi0[3] * xv;
            a4 = wi0[4] * xv; a5 = wi0[5] * xv; a6 = wi0[6] * xv; a7 = wi0[7] * xv;
        } else {
            a0 = a1 = a2 = a3 = a4 = a5 = a6 = a7 = 0.f;
        }
        if (needRow) {
            const float* sp = s_buf[p];
#pragma unroll
            for (int i = 0; i < 16; ++i) {
                const float hv = sp[(i << 6) | lane];
                a0 = __fmaf_rn(W[0][i], hv, a0);
                a1 = __fmaf_rn(W[1][i], hv, a1);
                a2 = __fmaf_rn(W[2][i], hv, a2);
                a3 = __fmaf_rn(W[3][i], hv, a3);
                a4 = __fmaf_rn(W[4][i], hv, a4);
                a5 = __fmaf_rn(W[5][i], hv, a5);
                a6 = __fmaf_rn(W[6][i], hv, a6);
                a7 = __fmaf_rn(W[7][i], hv, a7);
            }
        }

        // ---- scatter-butterfly reduce: lane l ends with 64-lane sum of acc (l&7) ----
        float e;
        {
            const int l1 = lane & 1, l2 = lane & 2, l4 = lane & 4;
            const float s0 = __shfl_xor(a0, 1, 64), s1 = __shfl_xor(a1, 1, 64);
            const float s2 = __shfl_xor(a2, 1, 64), s3 = __shfl_xor(a3, 1, 64);
            const float s4 = __shfl_xor(a4, 1, 64), s5 = __shfl_xor(a5, 1, 64);
            const float s6 = __shfl_xor(a6, 1, 64), s7 = __shfl_xor(a7, 1, 64);
            const float c0 = l1 ? (a1 + s1) : (a0 + s0);
            const float c1 = l1 ? (a3 + s3) : (a2 + s2);
            const float c2 = l1 ? (a5 + s5) : (a4 + s4);
            const float c3 = l1 ? (a7 + s7) : (a6 + s6);
            const float u0 = __shfl_xor(c0, 2, 64), u1 = __shfl_xor(c1, 2, 64);
            const float u2 = __shfl_xor(c2, 2, 64), u3 = __shfl_xor(c3, 2, 64);
            const float d0 = l2 ? (c1 + u1) : (c0 + u0);
            const float d1 = l2 ? (c3 + u3) : (c2 + u2);
            const float v0 = __shfl_xor(d0, 4, 64), v1 = __shfl_xor(d1, 4, 64);
            e = l4 ? (d1 + v1) : (d0 + v0);
            e += __shfl_xor(e, 8, 64);
            e += __shfl_xor(e, 16, 64);
            e += __shfl_xor(e, 32, 64);
        }

        // ---- epilogue ----
        if (isH) {
            float add;
            if (layer == 0) {
                add = biasL;
            } else {
                const uint32_t want = preTagB + (uint32_t)t;
                bool bad = ((uint32_t)(pre >> 32) != want);
                while (__any(bad)) {
                    if (bad) {
                        pre = __hip_atomic_load(preIn + (size_t)t * 4096 + (j0 << 2) + k,
                                                __ATOMIC_RELAXED, __HIP_MEMORY_SCOPE_AGENT);
                        bad = ((uint32_t)(pre >> 32) != want);
                    }
                }
                add = __uint_as_float((uint32_t)pre);   // preact holds Wih.x + b_ih + b_hh
            }
            const float val = e + add;
            // gate nonlinearity: k&3 == 2 is the g-gate (tanh), others sigmoid
            const float av = ((lane & 3) == 2) ? ftanh(val) : fsig(val);
            const int gb = lane & ~3;
            const float iv = __shfl(av, gb + 0, 64);
            const float fv = __shfl(av, gb + 1, 64);
            const float gv = __shfl(av, gb + 2, 64);
            const float ov = __shfl(av, gb + 3, 64);
            c = __fmaf_rn(fv, c, iv * gv);
            const float h = ov * ftanh(c);
            if (lane < 8 && (lane & 3) == 0) {
                const u64 slot = ((u64)(myTagB + (uint32_t)t) << 32)
                               | (u64)__float_as_uint(h);
                const int jj = j0 + (lane >> 2);
                __hip_atomic_store(valOut + (size_t)((uint32_t)t & srcRowM) * HD + jj, slot,
                                   __ATOMIC_RELAXED, __HIP_MEMORY_SCOPE_AGENT);
                if (layer != 2)
                    __hip_atomic_store(mirOut + (size_t)t * HD + jj, slot,
                                       __ATOMIC_RELAXED, __HIP_MEMORY_SCOPE_AGENT);
            }
        } else {
            const float val = e + biasL;
            if (lane < 8) {
                const u64 slot = ((u64)(preTagB + (uint32_t)t) << 32)
                               | (u64)__float_as_uint(val);
                __hip_atomic_store(preOut + (size_t)t * 4096 + (j0 << 2) + lane,
                                   slot, __ATOMIC_RELAXED, __HIP_MEMORY_SCOPE_AGENT);
            }
        }
    }
}

__global__ __launch_bounds__(256)
void final_kernel(const float* __restrict__ w_lin,
                  const float* __restrict__ b_lin,
                  float*       __restrict__ out)
{
    __shared__ float red[256];
    const int tid = threadIdx.x;
    const u64* hrow = g_ring + (size_t)((T_STEPS - 1) & (RINGR - 1)) * HD;
    float s = 0.f;
#pragma unroll
    for (int i = 0; i < 4; ++i) {
        const int kk = tid + 256 * i;
        s += __uint_as_float((uint32_t)hrow[kk]) * w_lin[kk];
    }
    red[tid] = s;
    __syncthreads();
    for (int o = 128; o > 0; o >>= 1) {
        if (tid < o) red[tid] += red[tid + o];
        __syncthreads();
    }
    if (tid == 0) out[0] = red[0] + b_lin[0];
}

extern "C" void kernel_launch(void* const* d_in, const int* in_sizes, int n_in,
                              void* d_out, int out_size, void* d_ws, size_t ws_size,
                              hipStream_t stream)
{
    (void)in_sizes; (void)n_in; (void)out_size; (void)d_ws; (void)ws_size;

    const float* seq   = (const float*)d_in[0];
    const float* w_ih0 = (const float*)d_in[1];
    const float* w_hh0 = (const float*)d_in[2];
    const float* b_ih0 = (const float*)d_in[3];
    const float* b_hh0 = (const float*)d_in[4];
    const float* w_ih1 = (const float*)d_in[5];
    const float* w_hh1 = (const float*)d_in[6];
    const float* b_ih1 = (const float*)d_in[7];
    const float* b_hh1 = (const float*)d_in[8];
    const float* w_ih2 = (const float*)d_in[9];
    const float* w_hh2 = (const float*)d_in[10];
    const float* b_ih2 = (const float*)d_in[11];
    const float* b_hh2 = (const float*)d_in[12];
    const float* w_lin = (const float*)d_in[13];
    const float* b_lin = (const float*)d_in[14];

    // Tag hygiene (previous replay left matching tags in the h buffers).
    zero_bufs<<<dim3(2048), dim3(256), 0, stream>>>();

    // Blocks [0,384) = h-role (128/layer); [384,640) = x-role (128 for L1, L2).
    fused_scan<<<dim3(640), dim3(256), 0, stream>>>(
        seq,
        w_ih0, w_hh0, b_ih0, b_hh0,
        w_ih1, w_hh1, b_ih1, b_hh1,
        w_ih2, w_hh2, b_ih2, b_hh2);

    final_kernel<<<dim3(1), dim3(256), 0, stream>>>(w_lin, b_lin, (float*)d_out);
}